// Round 14
// baseline (296.530 us; speedup 1.0000x reference)
//
#include <hip/hip_runtime.h>

// LSTM round 13b: R10 frame (8 batches/wave, 1024 waves = 1/SIMD, f16 MFMA,
// pipelined chain-1, no LDS, no barriers) + sigma-permuted K-layout:
// B k-slot 8kg+e holds h[4kg+e] (e<4) / h[16+4kg+e-4] (e>=4), compensated in
// Ahh load. Lane's B-frag = {own 4 h} U {lane^8's 4 h} -> feedback via 2
// v_mov_dpp row_ror:8 (VALU, no LDS pipe) + 4 cndmask. Replaces 4 ds_bpermute.
// h/x packed with v_cvt_pkrtz_f16_f32. Cells = R10 exp/rcp (saturation-exact).

typedef __attribute__((ext_vector_type(8))) _Float16 half8;
typedef __attribute__((ext_vector_type(4))) float f32x4;
typedef __attribute__((ext_vector_type(4))) unsigned int u32x4;

static constexpr int BB  = 8192;
static constexpr int TT  = 512;
static constexpr int NIN = 5;
static constexpr int HH  = 32;

__device__ __forceinline__ unsigned int pkrtz(float a, float b) {
    auto h = __builtin_amdgcn_cvt_pkrtz(a, b);   // __fp16 ext_vector(2)
    return __builtin_bit_cast(unsigned int, h);
}
__device__ __forceinline__ float fast_sigmoid(float x) {
    float e = __builtin_amdgcn_exp2f(-1.4426950408889634f * x);
    return __builtin_amdgcn_rcpf(1.0f + e);
}
__device__ __forceinline__ float fast_tanh(float x) {
    float e = __builtin_amdgcn_exp2f(2.8853900817779268f * x);
    return 1.0f - 2.0f * __builtin_amdgcn_rcpf(1.0f + e);
}
// lane-xor-8 exchange within rows of 16: DPP row_ror:8 (pure VALU, 2 cyc)
__device__ __forceinline__ unsigned int xor8_dpp(unsigned int v) {
    return (unsigned int)__builtin_amdgcn_mov_dpp((int)v, 0x128, 0xF, 0xF, false);
}

__global__ __launch_bounds__(64) void lstm_dpp(
    const float* __restrict__ x,     // [B, T, 5]
    const float* __restrict__ W_ih,  // [128, 5]
    const float* __restrict__ W_hh,  // [128, 32]
    const float* __restrict__ b_ih,  // [128]
    const float* __restrict__ b_hh,  // [128]
    const float* __restrict__ W_fc,  // [1, 32]
    const float* __restrict__ b_fc,  // [1]
    float* __restrict__ out)         // [B]
{
    const int lane = threadIdx.x & 63;
    const int col  = lane & 15;      // batch (dup x2)
    const int kg   = lane >> 4;      // k-group
    const int b0   = blockIdx.x * 8;
    const int bloc = col & 7;
    const bool jlow = (col < 8);
    const int jbase = 4 * kg + (jlow ? 0 : 16);

    // ---- A-fragments (loop-invariant). Tile t4: gate rows gr=16*t4+col.
    // Ahh k-slot e maps to h[sigma] with sigma = 4kg+e (e<4) | 16+4kg+e-4 (e>=4).
    // Ax (kg0 only): slots0-4=W_ih@f16, slot5=bias_hi, slot6=bias_lo, slot7=0.
    half8 Ahh[8], Ax[8];
#pragma unroll
    for (int t4 = 0; t4 < 8; ++t4) {
        const int gr = 16 * t4 + col;
#pragma unroll
        for (int e = 0; e < 8; ++e) {
            const int sigma = (e < 4) ? (4 * kg + e) : (16 + 4 * kg + (e - 4));
            Ahh[t4][e] = (_Float16)W_hh[gr * HH + sigma];
        }
        half8 v;
#pragma unroll
        for (int e = 0; e < 8; ++e) v[e] = (_Float16)0.f;
        if (kg == 0) {
#pragma unroll
            for (int e = 0; e < NIN; ++e) v[e] = (_Float16)W_ih[gr * NIN + e];
            float bias = b_ih[gr] + b_hh[gr];
            _Float16 bh_ = (_Float16)bias;
            v[5] = bh_;
            v[6] = (_Float16)(bias - (float)bh_);
        }
        Ax[t4] = v;
    }

    const bool xk = (kg == 0);

    // ---- x stream: per-lane loads of own batch row (8-lane broadcast) ----
    const float* px = x + (size_t)(b0 + bloc) * TT * NIN;
    float x0 = px[0], x1 = px[1], x2 = px[2], x3 = px[3], x4 = px[4];

    float c0 = 0.f, c1 = 0.f, c2 = 0.f, c3 = 0.f;
    float h0 = 0.f, h1 = 0.f, h2 = 0.f, h3 = 0.f;
    unsigned int p0 = 0, p1 = 0;     // packed own h pair (h=0 at t=0)
    const f32x4 z = {0.f, 0.f, 0.f, 0.f};

    auto make_bx = [&](float v0, float v1, float v2, float v3, float v4) -> half8 {
        unsigned w0 = pkrtz(v0, v1);
        unsigned w1 = pkrtz(v2, v3);
        unsigned w2 = pkrtz(v4, 1.0f);          // slot5 = 1.0
        unsigned w3 = 0x00003C00u;              // slot6 = 1.0, slot7 = 0
        u32x4 u = {xk ? w0 : 0u, xk ? w1 : 0u, xk ? w2 : 0u, xk ? w3 : 0u};
        return __builtin_bit_cast(half8, u);
    };

    // ---- prologue: chain-1 for t=0 ----
    f32x4 accN[8];
    {
        half8 bx0 = make_bx(x0, x1, x2, x3, x4);
#pragma unroll
        for (int t4 = 0; t4 < 8; ++t4)
            accN[t4] = __builtin_amdgcn_mfma_f32_16x16x32_f16(Ax[t4], bx0, z, 0, 0, 0);
    }

#pragma unroll 1
    for (int t = 0; t < TT; ++t) {
        // (1) prefetch x(t+1)
        const size_t off = (size_t)((t + 1 < TT) ? (t + 1) : t) * NIN;
        float n0 = px[off + 0], n1 = px[off + 1], n2 = px[off + 2],
              n3 = px[off + 3], n4 = px[off + 4];

        // (2) build bh from packed pairs: own (p0,p1) + partner via DPP xor8
        unsigned int q0 = xor8_dpp(p0);
        unsigned int q1 = xor8_dpp(p1);
        u32x4 bhu = {jlow ? p0 : q0, jlow ? p1 : q1,
                     jlow ? q0 : p0, jlow ? q1 : p1};
        half8 bh = __builtin_bit_cast(half8, bhu);

        // (3) chain-2: acc = Ahh*bh + accN
        f32x4 acc[8];
#pragma unroll
        for (int t4 = 0; t4 < 8; ++t4)
            acc[t4] = __builtin_amdgcn_mfma_f32_16x16x32_f16(Ahh[t4], bh, accN[t4], 0, 0, 0);

        // (4) chain-1 for t+1 (independent; fills cell-phase matrix idle)
        half8 bxn = make_bx(n0, n1, n2, n3, n4);
#pragma unroll
        for (int t4 = 0; t4 < 8; ++t4)
            accN[t4] = __builtin_amdgcn_mfma_f32_16x16x32_f16(Ax[t4], bxn, z, 0, 0, 0);

        // (5) 4 cells (R10 exp/rcp form, saturation-exact)
#pragma unroll
        for (int r = 0; r < 4; ++r) {
            float gi = jlow ? acc[0][r] : acc[1][r];
            float gf = jlow ? acc[2][r] : acc[3][r];
            float gg = jlow ? acc[4][r] : acc[5][r];
            float go = jlow ? acc[6][r] : acc[7][r];
            float iv = fast_sigmoid(gi);
            float fv = fast_sigmoid(gf);
            float gv = fast_tanh(gg);
            float ov = fast_sigmoid(go);
            float cc = (r == 0 ? c0 : r == 1 ? c1 : r == 2 ? c2 : c3);
            cc = fmaf(fv, cc, iv * gv);
            float hh = ov * fast_tanh(cc);
            if (r == 0) { c0 = cc; h0 = hh; }
            else if (r == 1) { c1 = cc; h1 = hh; }
            else if (r == 2) { c2 = cc; h2 = hh; }
            else { c3 = cc; h3 = hh; }
        }

        // (6) pack own h pair for next step's bh
        p0 = pkrtz(h0, h1);
        p1 = pkrtz(h2, h3);

        x0 = n0; x1 = n1; x2 = n2; x3 = n3; x4 = n4;
    }

    // ---- head: out[b] = sum_j h[b][j]*W_fc[j] + b_fc ----
    float v = h0 * W_fc[jbase + 0] + h1 * W_fc[jbase + 1]
            + h2 * W_fc[jbase + 2] + h3 * W_fc[jbase + 3];
    v += __shfl_xor(v, 8);
    v += __shfl_xor(v, 16);
    v += __shfl_xor(v, 32);
    if (lane < 8) out[b0 + lane] = v + b_fc[0];
}

extern "C" void kernel_launch(void* const* d_in, const int* in_sizes, int n_in,
                              void* d_out, int out_size, void* d_ws, size_t ws_size,
                              hipStream_t stream) {
    const float* x    = (const float*)d_in[0];
    const float* W_ih = (const float*)d_in[1];
    const float* W_hh = (const float*)d_in[2];
    const float* b_ih = (const float*)d_in[3];
    const float* b_hh = (const float*)d_in[4];
    const float* W_fc = (const float*)d_in[5];
    const float* b_fc = (const float*)d_in[6];
    float* out = (float*)d_out;

    lstm_dpp<<<dim3(BB / 8), dim3(64), 0, stream>>>(
        x, W_ih, W_hh, b_ih, b_hh, W_fc, b_fc, out);
}